// Round 13
// baseline (155.502 us; speedup 1.0000x reference)
//
#include <hip/hip_runtime.h>
#include <hip/hip_bf16.h>

#define T_TOT 2304
#define DDIM  1024
#define NH    16
#define DK    64
#define SLEN  128
#define SEQ   2048

typedef __bf16 bf16x8 __attribute__((ext_vector_type(8)));
typedef __bf16 bf16x4 __attribute__((ext_vector_type(4)));
typedef float  f32x4  __attribute__((ext_vector_type(4)));
typedef float  f32x16 __attribute__((ext_vector_type(16)));

__device__ __forceinline__ void async_copy16(const void* gsrc, void* ldst) {
  __builtin_amdgcn_global_load_lds(
      (const __attribute__((address_space(1))) void*)gsrc,
      (__attribute__((address_space(3))) void*)ldst, 16, 0, 0);
}

// LDS-only barrier: waits own LDS ops, joins waves, does NOT drain vmcnt.
__device__ __forceinline__ void lds_barrier() {
  __asm__ volatile("s_waitcnt lgkmcnt(0)\n\ts_barrier" ::: "memory");
}

// ---------------- convert: x -> bf16 (vectorized); W[h][d][n] -> Wt[m][h][n][d] via LDS transpose
__global__ __launch_bounds__(256) void convert_kernel(
    const float* __restrict__ x,
    const float* __restrict__ Wq, const float* __restrict__ Wk,
    const float* __restrict__ Wv, const float* __restrict__ Wqs,
    const float* __restrict__ Wks, const float* __restrict__ Wvs,
    __bf16* __restrict__ xb, __bf16* __restrict__ Wt) {
  const int b = blockIdx.x;
  const int tid = threadIdx.x;
  if (b < 576) {
    const float4* xin = (const float4*)x;
#pragma unroll
    for (int it = 0; it < 4; ++it) {
      int idx4 = b * 1024 + it * 256 + tid;
      float4 v = xin[idx4];
      bf16x4 o;
      o[0] = (__bf16)v.x; o[1] = (__bf16)v.y; o[2] = (__bf16)v.z; o[3] = (__bf16)v.w;
      *(bf16x4*)(xb + (size_t)idx4 * 4) = o;
    }
    return;
  }
  __shared__ float tile[64 * 65];
  const int wb = b - 576;
  const int m  = wb >> 8;
  const int rem = wb & 255;
  const int h  = rem >> 4;
  const int dt = rem & 15;
  const int d0 = dt * 64;
  const float* Wsrc = (m == 0 ? Wq : m == 1 ? Wk : m == 2 ? Wv
                      : m == 3 ? Wqs : m == 4 ? Wks : Wvs) + (size_t)h * (DDIM * DK);
#pragma unroll
  for (int rr = 0; rr < 4; ++rr) {
    int drow = rr * 16 + (tid >> 4);
    int nc   = (tid & 15) * 4;
    float4 v = *(const float4*)(Wsrc + (size_t)(d0 + drow) * DK + nc);
    tile[(nc + 0) * 65 + drow] = v.x;
    tile[(nc + 1) * 65 + drow] = v.y;
    tile[(nc + 2) * 65 + drow] = v.z;
    tile[(nc + 3) * 65 + drow] = v.w;
  }
  __syncthreads();
  {
    int n  = tid >> 2;
    int rg = (tid & 3) * 16;
    __bf16* dst = Wt + (((size_t)(m * NH + h)) * DK + n) * DDIM + d0 + rg;
    bf16x8 o0, o1;
#pragma unroll
    for (int e = 0; e < 8; e++) o0[e] = (__bf16)tile[n * 65 + rg + e];
#pragma unroll
    for (int e = 0; e < 8; e++) o1[e] = (__bf16)tile[n * 65 + rg + 8 + e];
    *(bf16x8*)dst = o0;
    *(bf16x8*)(dst + 8) = o1;
  }
}

// ---------------- proj v2: m97-shape GEMM 128x128 tile, N=1024 (all 16 heads fused)
// q is pre-scaled by scal[h]*log2(e) so attn softmax can use exp2 directly.
__global__ __launch_bounds__(256) void proj_kernel(
    const __bf16* __restrict__ xb, const __bf16* __restrict__ Wt,
    const float* __restrict__ scal,
    __bf16* __restrict__ qkv, __bf16* __restrict__ vt) {
  const int ntile = blockIdx.x;   // 0..7
  const int rt    = blockIdx.y;   // 0..17
  const int which = blockIdx.z;   // 0=q 1=k 2=v
  const int r0    = rt * 128;
  const int m     = (rt == 0 || rt == 17) ? which + 3 : which;

  __shared__ __bf16 Xs[128 * 64];
  __shared__ __bf16 Wsh[128 * 64];

  const int tid  = threadIdx.x;
  const int wave = tid >> 6, lane = tid & 63;
  const int quad = lane >> 4, lc = lane & 15;
  const int wr   = wave >> 1, wc = wave & 1;
  const int h    = ntile * 2 + wc;

  const __bf16* Wbase = Wt + ((size_t)m * NH) * (DK * DDIM) + (size_t)(ntile * 128) * DDIM;

  const f32x4 fz = {0.f, 0.f, 0.f, 0.f};
  f32x4 acc[4][4];
#pragma unroll
  for (int i = 0; i < 4; i++)
#pragma unroll
    for (int j = 0; j < 4; j++) acc[i][j] = fz;

  for (int k0 = 0; k0 < DDIM; k0 += 64) {
#pragma unroll
    for (int it = 0; it < 4; ++it) {
      int L = it * 256 + tid;
      int row = L >> 3, c = (L & 7) ^ ((L >> 3) & 7);
      async_copy16(xb + (size_t)(r0 + row) * DDIM + k0 + c * 8,
                   (char*)Xs + (size_t)(it * 256 + wave * 64) * 16);
    }
#pragma unroll
    for (int it = 0; it < 4; ++it) {
      int L = it * 256 + tid;
      int row = L >> 3, c = (L & 7) ^ ((L >> 3) & 7);
      async_copy16(Wbase + (size_t)row * DDIM + k0 + c * 8,
                   (char*)Wsh + (size_t)(it * 256 + wave * 64) * 16);
    }
    __syncthreads();
#pragma unroll
    for (int kk = 0; kk < 2; kk++) {
      bf16x8 afr[4], bfr[4];
#pragma unroll
      for (int i = 0; i < 4; i++) {
        int row = wr * 64 + i * 16 + lc;
        int ch  = (kk * 4 + quad) ^ (row & 7);
        afr[i] = *(const bf16x8*)(Xs + (row * 8 + ch) * 8);
      }
#pragma unroll
      for (int j = 0; j < 4; j++) {
        int row = wc * 64 + j * 16 + lc;
        int ch  = (kk * 4 + quad) ^ (row & 7);
        bfr[j] = *(const bf16x8*)(Wsh + (row * 8 + ch) * 8);
      }
#pragma unroll
      for (int i = 0; i < 4; i++)
#pragma unroll
        for (int j = 0; j < 4; j++)
          acc[i][j] = __builtin_amdgcn_mfma_f32_16x16x32_bf16(afr[i], bfr[j], acc[i][j], 0, 0, 0);
    }
    __syncthreads();
  }

  const float qscale = (which == 0) ? scal[h] * 1.44269504088896f : 1.0f;
  float inv4[4][4];
#pragma unroll
  for (int i = 0; i < 4; i++) {
#pragma unroll
    for (int r = 0; r < 4; r++) {
      float s = 0.f;
#pragma unroll
      for (int j = 0; j < 4; j++) { float v = acc[i][j][r]; s += v * v; }
#pragma unroll
      for (int off = 1; off < 16; off <<= 1) s += __shfl_xor(s, off, 64);
      inv4[i][r] = qscale / fmaxf(sqrtf(s), 1e-12f);
    }
  }
  if (which == 2) {
    __bf16* vtp = vt + (size_t)h * (DK * T_TOT);
#pragma unroll
    for (int i = 0; i < 4; i++) {
      int rowbase = r0 + wr * 64 + i * 16 + quad * 4;
#pragma unroll
      for (int j = 0; j < 4; j++) {
        bf16x4 o;
#pragma unroll
        for (int r = 0; r < 4; r++) o[r] = (__bf16)(acc[i][j][r] * inv4[i][r]);
        *(bf16x4*)(vtp + (size_t)(j * 16 + lc) * T_TOT + rowbase) = o;
      }
    }
  } else {
    __bf16* outp = qkv + ((size_t)(which * NH + h)) * ((size_t)T_TOT * DK);
#pragma unroll
    for (int i = 0; i < 4; i++)
#pragma unroll
      for (int r = 0; r < 4; r++) {
        int row = r0 + wr * 64 + i * 16 + quad * 4 + r;
#pragma unroll
        for (int j = 0; j < 4; j++)
          outp[(size_t)row * DK + j * 16 + lc] = (__bf16)(acc[i][j][r] * inv4[i][r]);
      }
  }
}

// ---------------- flash attention v12: split-K(4) per (h,64q), kv-sliced S,
// 32x32x16 PV, fixed-shift softmax; unnormalized partials, pure-sum combine.
__global__ __launch_bounds__(256, 3) void attn_kernel(
    const __bf16* __restrict__ qkv, const __bf16* __restrict__ vt,
    float* __restrict__ Opart, float* __restrict__ Lpart) {
  const int b    = blockIdx.x;          // 0..2303
  const int h    = b & 15;
  const int rest = b >> 4;              // 0..143
  const int qg   = 35 - (rest >> 2);    // big work first
  const int si   = rest & 3;            // kv split index 0..3
  const int q0b  = qg * 64;
  const int tid  = threadIdx.x;
  const int wave = tid >> 6, lane = tid & 63;
  const int quad = lane >> 4, lc = lane & 15;
  const int l32  = lane & 31, hi = lane >> 5;

  const __bf16* qp = qkv + ((size_t)h) * ((size_t)T_TOT * DK);
  const __bf16* kp = qkv + ((size_t)(NH + h)) * ((size_t)T_TOT * DK);
  const __bf16* vp = vt + (size_t)h * (DK * T_TOT);

  __shared__ __bf16 Ks[2][64 * 64];     // 8 KB x2
  __shared__ __bf16 Vs[2][64 * 64];     // 8 KB x2
  __shared__ __bf16 Ps[64 * 64];        // 8 KB
  __shared__ float  lred[4][64];

  // Q B-frags (persistent): B[k=d][n=q=qt*16+lc]
  bf16x8 qf[4][2];
#pragma unroll
  for (int qt = 0; qt < 4; qt++)
#pragma unroll
    for (int kk = 0; kk < 2; kk++)
      qf[qt][kk] = *(const bf16x8*)(qp + (size_t)(q0b + qt * 16 + lc) * DK + kk * 32 + quad * 8);

  f32x16 acc_o;                         // O^T tile [32d][32q] per wave
#pragma unroll
  for (int e = 0; e < 16; e++) acc_o[e] = 0.f;
  float lp[4] = {0.f, 0.f, 0.f, 0.f};

  // kv quarter-range for this split
  const int jsAll = (q0b >= SLEN + SEQ) ? 2 : 0;
  const int n     = qg - jsAll + 1;
  const int j0    = jsAll + ((n * si) >> 2);
  const int j1    = jsAll + ((n * (si + 1)) >> 2) - 1;

  auto stage = [&](int j, int bufi) {
    const __bf16* kT = kp + (size_t)j * 64 * DK;
#pragma unroll
    for (int it = 0; it < 2; ++it) {
      int L = it * 256 + tid;
      int row = L >> 3, c = (L & 7) ^ ((L >> 3) & 7);
      async_copy16(kT + (size_t)row * DK + c * 8,
                   (char*)&Ks[bufi][0] + (size_t)(it * 256 + wave * 64) * 16);
    }
#pragma unroll
    for (int it = 0; it < 2; ++it) {
      int L = it * 256 + tid;
      int d = L >> 3, c = (L & 7) ^ ((L >> 3) & 7);
      async_copy16(vp + (size_t)d * T_TOT + j * 64 + c * 8,
                   (char*)&Vs[bufi][0] + (size_t)(it * 256 + wave * 64) * 16);
    }
  };

  int cur = 0;
  if (j0 <= j1) stage(j0, 0);

  const int d0 = (wave >> 1) * 32;      // PV d-tile
  const int q0 = (wave & 1) * 32;       // PV q-tile

  for (int j = j0; j <= j1; ++j) {
    __syncthreads();                    // drain staging of tile j; protect Ps
    if (j < j1) stage(j + 1, cur ^ 1);

    const bool diag = (j == qg);

    // S^T slice: kv = wave*16 + quad*4 + r ; q = qt*16 + lc
    bf16x8 kA[2];
#pragma unroll
    for (int kk = 0; kk < 2; kk++) {
      int row = wave * 16 + lc;
      kA[kk] = *(const bf16x8*)(&Ks[cur][(row * 8 + ((kk * 4 + quad) ^ (lc & 7))) * 8]);
    }
    f32x4 s[4];
#pragma unroll
    for (int qt = 0; qt < 4; qt++) {
      s[qt] = (f32x4){0.f, 0.f, 0.f, 0.f};
#pragma unroll
      for (int kk = 0; kk < 2; kk++)
        s[qt] = __builtin_amdgcn_mfma_f32_16x16x32_bf16(kA[kk], qf[qt][kk], s[qt], 0, 0, 0);
    }

    // fixed-shift softmax + P write
#pragma unroll
    for (int qt = 0; qt < 4; qt++) {
      if (diag) {
#pragma unroll
        for (int r = 0; r < 4; r++)
          if ((wave * 16 + quad * 4 + r) > (qt * 16 + lc)) s[qt][r] = -__builtin_inff();
      }
      bf16x4 pb;
#pragma unroll
      for (int r = 0; r < 4; r++) {
        float pe = exp2f(s[qt][r]);
        lp[qt] += pe;
        pb[r] = (__bf16)pe;
      }
      int el = (qt * 16 + lc) * 64 + (((wave * 2 + (quad >> 1)) ^ (lc & 7)) * 8) + (quad & 1) * 4;
      *(bf16x4*)(&Ps[el]) = pb;
    }

    lds_barrier();                      // P visible; prefetch stays in flight

    // O^T[32d][32q] += V^T P^T  (32x32x16 MFMA, 4 k-steps)
#pragma unroll
    for (int ks = 0; ks < 4; ks++) {
      int ch = (ks * 2 + hi) ^ (l32 & 7);
      bf16x8 vA = *(const bf16x8*)(&Vs[cur][((d0 + l32) * 8 + ch) * 8]);
      bf16x8 pB = *(const bf16x8*)(&Ps[((q0 + l32) * 8 + ch) * 8]);
      acc_o = __builtin_amdgcn_mfma_f32_32x32x16_bf16(vA, pB, acc_o, 0, 0, 0);
    }
    cur ^= 1;
  }

  // l reduction: quads via shuffle, waves via LDS; store per-block partials
#pragma unroll
  for (int qt = 0; qt < 4; qt++) {
    lp[qt] += __shfl_xor(lp[qt], 16, 64);
    lp[qt] += __shfl_xor(lp[qt], 32, 64);
  }
  lred[wave][quad * 16 + lc] = lp[quad];
  __syncthreads();
  if (wave == 0)
    Lpart[(size_t)b * 64 + lane] = lred[0][lane] + lred[1][lane] + lred[2][lane] + lred[3][lane];

  // store unnormalized O partial: [q][d] layout
  float* Ob = Opart + (size_t)b * 4096;
  const size_t rowbase = (size_t)(q0 + l32) * DK;
#pragma unroll
  for (int g = 0; g < 4; g++) {
    f32x4 o;
#pragma unroll
    for (int t = 0; t < 4; t++) o[t] = acc_o[g * 4 + t];
    *(f32x4*)(&Ob[rowbase + d0 + 4 * hi + 8 * g]) = o;
  }
}

// ---------------- combine: out = (O0+O1+O2+O3) / (l0+l1+l2+l3)
__global__ __launch_bounds__(256) void combine_kernel(
    const float* __restrict__ Opart, const float* __restrict__ Lpart,
    float* __restrict__ out) {
  const int b  = blockIdx.x;            // 0..575
  const int h  = b & 15;
  const int qg = b >> 4;
  const int bb = (((35 - qg) * 4) << 4) | h;   // split 0 block id; +16 per split
  const int tid = threadIdx.x;

  __shared__ float invl[64];
  if (tid < 64) {
    float l = 0.f;
#pragma unroll
    for (int sPart = 0; sPart < 4; sPart++)
      l += Lpart[(size_t)(bb + 16 * sPart) * 64 + tid];
    invl[tid] = 1.0f / l;
  }
  __syncthreads();

  const float* O0 = Opart + (size_t)bb * 4096;
  float* op = out + ((size_t)h * T_TOT + qg * 64) * DK;
#pragma unroll
  for (int it = 0; it < 4; ++it) {
    int i4 = it * 256 + tid;            // vec4 index, 0..1023
    f32x4 a = *(const f32x4*)(&O0[i4 * 4]);
#pragma unroll
    for (int sPart = 1; sPart < 4; sPart++) {
      f32x4 c = *(const f32x4*)(&O0[(size_t)sPart * 16 * 4096 + i4 * 4]);
#pragma unroll
      for (int r = 0; r < 4; r++) a[r] += c[r];
    }
    float iv = invl[i4 >> 4];
    f32x4 o;
#pragma unroll
    for (int r = 0; r < 4; r++) o[r] = a[r] * iv;
    *(f32x4*)(&op[i4 * 4]) = o;
  }
}

extern "C" void kernel_launch(void* const* d_in, const int* in_sizes, int n_in,
                              void* d_out, int out_size, void* d_ws, size_t ws_size,
                              hipStream_t stream) {
  const float* x    = (const float*)d_in[0];
  const float* Wq   = (const float*)d_in[1];
  const float* Wk   = (const float*)d_in[2];
  const float* Wv   = (const float*)d_in[3];
  const float* Wqs  = (const float*)d_in[4];
  const float* Wks  = (const float*)d_in[5];
  const float* Wvs  = (const float*)d_in[6];
  const float* scal = (const float*)d_in[7];
  float* out = (float*)d_out;

  char* ws = (char*)d_ws;
  size_t off = 0;
  __bf16* xb    = (__bf16*)(ws + off); off += (size_t)T_TOT * DDIM * 2;
  __bf16* Wt    = (__bf16*)(ws + off); off += (size_t)6 * NH * DK * DDIM * 2;
  __bf16* qkv   = (__bf16*)(ws + off); off += (size_t)2 * NH * T_TOT * DK * 2;
  __bf16* vt    = (__bf16*)(ws + off); off += (size_t)NH * DK * T_TOT * 2;
  float*  Opart = (float*)(ws + off);  off += (size_t)2304 * 4096 * 4;
  float*  Lpart = (float*)(ws + off);

  convert_kernel<<<2112, 256, 0, stream>>>(x, Wq, Wk, Wv, Wqs, Wks, Wvs, xb, Wt);
  proj_kernel<<<dim3(8, 18, 3), 256, 0, stream>>>(xb, Wt, scal, qkv, vt);
  attn_kernel<<<dim3(2304), 256, 0, stream>>>(qkv, vt, Opart, Lpart);
  combine_kernel<<<dim3(576), 256, 0, stream>>>(Opart, Lpart, out);
}